// Round 1
// baseline (409.600 us; speedup 1.0000x reference)
//
#include <hip/hip_runtime.h>

// EdgeFormerINT4Linear via INT8 dynamic quantization:
// y[m,o] = (sum_i xq[m,i]*q[o,i]) * (srow[m]*scale[o]) + bias[o]
// Round 2: (a) GEMM rebuilt as 256x256 / 8-wave / BK=128 double-buffered
// schedule with counted s_waitcnt vmcnt(8) (T3+T4) + setprio (T5), keeping the
// verified XOR-chunk LDS swizzle (T2) and verified 16x16x64 i8 C/D mapping.
// (b) the two prepasses fused into one grid-partitioned launch so the row
// quantization and weight pack run concurrently.

#define M_ROWS 8192
#define N_COLS 4096
#define K_DIM  4096
#define NT     (K_DIM / 128)   // 32 K-tiles of 128 bytes

typedef int int32x4 __attribute__((ext_vector_type(4)));

__device__ __forceinline__ void async16(const void* g, void* l) {
  __builtin_amdgcn_global_load_lds(
      (const __attribute__((address_space(1))) void*)g,
      (__attribute__((address_space(3))) void*)l,
      16 /*bytes*/, 0 /*offset*/, 0 /*aux*/);
}

// ---- fused prepass ----
// blocks [0, M_ROWS): per-row symmetric int8 quant of x (256 thr x 16 elems)
// blocks [M_ROWS, M_ROWS + N*K/4/256): q int32 -> int8 pack (1 int4/thread)
__global__ __launch_bounds__(256) void prep_kernel(const float4* __restrict__ x,
                                                   int* __restrict__ xq,
                                                   float* __restrict__ srow,
                                                   const int4* __restrict__ q,
                                                   int* __restrict__ q8) {
  const int t = threadIdx.x;
  if (blockIdx.x >= M_ROWS) {
    const int i = (blockIdx.x - M_ROWS) * 256 + t;
    const int4 v = q[i];
    q8[i] = (v.x & 0xff) | ((v.y & 0xff) << 8) | ((v.z & 0xff) << 16) | (v.w << 24);
    return;
  }
  const int row = blockIdx.x;
  const float4* xr = x + (size_t)row * (K_DIM / 4);
  float4 v[4];
  float am = 0.f;
#pragma unroll
  for (int j = 0; j < 4; ++j) {
    v[j] = xr[t + 256 * j];
    am = fmaxf(am, fmaxf(fmaxf(fabsf(v[j].x), fabsf(v[j].y)),
                         fmaxf(fabsf(v[j].z), fabsf(v[j].w))));
  }
#pragma unroll
  for (int off = 32; off > 0; off >>= 1)
    am = fmaxf(am, __shfl_down(am, off, 64));
  __shared__ float wmax[4];
  if ((t & 63) == 0) wmax[t >> 6] = am;
  __syncthreads();
  am = fmaxf(fmaxf(wmax[0], wmax[1]), fmaxf(wmax[2], wmax[3]));
  const float s   = am * (1.f / 127.f);
  const float inv = (am > 0.f) ? 127.f / am : 0.f;
  if (t == 0) srow[row] = s;
  int* o = xq + (size_t)row * (K_DIM / 4);
#pragma unroll
  for (int j = 0; j < 4; ++j) {
    int a = __float2int_rn(v[j].x * inv);
    int b = __float2int_rn(v[j].y * inv);
    int c = __float2int_rn(v[j].z * inv);
    int d = __float2int_rn(v[j].w * inv);
    o[t + 256 * j] = (a & 0xff) | ((b & 0xff) << 8) | ((c & 0xff) << 16) | (d << 24);
  }
}

// ---- GEMM: A[M,K] int8 row-major, B[N,K] int8 row-major (B^T form) ----
// 512 threads = 8 waves (2M x 4N), tile 256x256, BK=128 bytes.
// Wave tile: 128x64. Double-buffered LDS (2 x 32KB x 2 operands = 128 KiB).
// Per K-tile: 8 global_load_lds/thread issued EARLY, counted vmcnt(8) so the
// next tile's loads stay in flight across the barrier (never drain to 0 in
// the main loop). Verified 16B-chunk XOR swizzle: chunk c of row r sourced
// from col-chunk (c ^ (r&7)); read back with kc ^ (lm&7).
__global__ __launch_bounds__(512, 2) void gemm_i8_kernel(
    const char* __restrict__ A, const char* __restrict__ B,
    const float* __restrict__ scale, const float* __restrict__ srow,
    const float* __restrict__ bias, float* __restrict__ out) {
  __shared__ __attribute__((aligned(16))) char sA[2][32768];
  __shared__ __attribute__((aligned(16))) char sB[2][32768];

  const int tid  = threadIdx.x;
  const int lane = tid & 63;
  const int w    = tid >> 6;     // 0..7
  const int wr   = w >> 2;       // 0..1 : M half (128 rows)
  const int wc   = w & 3;        // 0..3 : N quarter (64 cols)
  const int lm   = lane & 15;
  const int lk   = lane >> 4;

  const int m0 = blockIdx.y * 256;
  const int n0 = blockIdx.x * 256;

  // staging: 2048 chunks of 16B per operand per tile; 4 chunks/thread.
  const char* gA[4];
  const char* gB[4];
  int dst[4];
#pragma unroll
  for (int qq = 0; qq < 4; ++qq) {
    const int ch = qq * 512 + tid;        // chunk 0..2047
    const int r  = ch >> 3;               // tile row 0..255
    const int sc = (ch & 7) ^ (r & 7);    // swizzled source col-chunk
    dst[qq] = ch * 16;                    // linear LDS dest (wave-uniform+lane*16)
    gA[qq]  = A + (size_t)(m0 + r) * K_DIM + sc * 16;
    gB[qq]  = B + (size_t)(n0 + r) * K_DIM + sc * 16;
  }

  // read-side bases (bytes). row*128 B/row; xor term depends only on lm&7.
  const int aBase = (wr * 128 + lm) * 128;
  const int bBase = (wc * 64 + lm) * 128;
  const int swz0  = ((0 * 4 + lk) ^ (lm & 7)) * 16;   // ks=0 chunk
  const int swz1  = ((1 * 4 + lk) ^ (lm & 7)) * 16;   // ks=1 chunk

  int32x4 acc[8][4];
#pragma unroll
  for (int i = 0; i < 8; ++i)
#pragma unroll
    for (int j = 0; j < 4; ++j) acc[i][j] = (int32x4){0, 0, 0, 0};

#define STAGE(buf, k0)                                   \
  {                                                      \
    _Pragma("unroll")                                    \
    for (int qq = 0; qq < 4; ++qq) {                     \
      async16(gA[qq] + (k0), &sA[buf][dst[qq]]);         \
      async16(gB[qq] + (k0), &sB[buf][dst[qq]]);         \
    }                                                    \
  }

#define TILE(buf)                                                              \
  {                                                                            \
    const char* pa = sA[buf];                                                  \
    const char* pb = sB[buf];                                                  \
    _Pragma("unroll")                                                          \
    for (int ks = 0; ks < 2; ++ks) {                                           \
      const int sz = ks ? swz1 : swz0;                                         \
      int32x4 bf[4];                                                           \
      _Pragma("unroll")                                                        \
      for (int j = 0; j < 4; ++j)                                              \
        bf[j] = *(const int32x4*)(pb + bBase + j * 2048 + sz);                 \
      _Pragma("unroll")                                                        \
      for (int mh = 0; mh < 2; ++mh) {                                         \
        int32x4 af[4];                                                         \
        _Pragma("unroll")                                                      \
        for (int ii = 0; ii < 4; ++ii)                                         \
          af[ii] = *(const int32x4*)(pa + aBase + (mh * 4 + ii) * 2048 + sz);  \
        __builtin_amdgcn_s_setprio(1);                                         \
        _Pragma("unroll")                                                      \
        for (int ii = 0; ii < 4; ++ii)                                         \
          _Pragma("unroll")                                                    \
          for (int j = 0; j < 4; ++j)                                          \
            acc[mh * 4 + ii][j] = __builtin_amdgcn_mfma_i32_16x16x64_i8(       \
                af[ii], bf[j], acc[mh * 4 + ii][j], 0, 0, 0);                  \
        __builtin_amdgcn_s_setprio(0);                                         \
      }                                                                        \
    }                                                                          \
  }

  STAGE(0, 0);
  for (int t = 0; t < NT; t += 2) {
    // tile t in buf0; stage tile t+1 into buf1, wait only for tile t's 8.
    STAGE(1, (t + 1) * 128);
    asm volatile("s_waitcnt vmcnt(8)" ::: "memory");
    __builtin_amdgcn_s_barrier();
    asm volatile("" ::: "memory");
    TILE(0);
    asm volatile("" ::: "memory");
    __builtin_amdgcn_s_barrier();   // all waves done reading buf0
    if (t + 2 < NT) {
      STAGE(0, (t + 2) * 128);
      asm volatile("s_waitcnt vmcnt(8)" ::: "memory");
    } else {
      asm volatile("s_waitcnt vmcnt(0)" ::: "memory");
    }
    __builtin_amdgcn_s_barrier();
    asm volatile("" ::: "memory");
    TILE(1);
    asm volatile("" ::: "memory");
    __builtin_amdgcn_s_barrier();   // all waves done reading buf1
  }

  // epilogue: C/D layout col=lane&15 (n), row=(lane>>4)*4+reg (m) — verified.
#pragma unroll
  for (int j = 0; j < 4; ++j) {
    const int o    = n0 + wc * 64 + j * 16 + lm;
    const float so = scale[o];
    const float bz = bias[o];
#pragma unroll
    for (int i = 0; i < 8; ++i) {
      const int mbase = m0 + wr * 128 + i * 16 + lk * 4;
#pragma unroll
      for (int r = 0; r < 4; ++r) {
        const int m = mbase + r;
        out[(size_t)m * N_COLS + o] = (float)acc[i][j][r] * (so * srow[m]) + bz;
      }
    }
  }
#undef STAGE
#undef TILE
}

extern "C" void kernel_launch(void* const* d_in, const int* in_sizes, int n_in,
                              void* d_out, int out_size, void* d_ws, size_t ws_size,
                              hipStream_t stream) {
  const float* x     = (const float*)d_in[0];   // [4,2048,4096] fp32
  const int*   q     = (const int*)d_in[1];     // [4096,4096] int32 in [-8,7]
  const float* scale = (const float*)d_in[2];   // [4096]
  const float* bias  = (const float*)d_in[3];   // [4096]
  float* out = (float*)d_out;                   // [8192,4096] fp32

  // workspace: A8 (32 MiB) | B8 (16 MiB) | srow (32 KiB)
  char*  A8   = (char*)d_ws;
  char*  B8   = (char*)d_ws + (size_t)M_ROWS * K_DIM;
  float* srow = (float*)((char*)B8 + (size_t)N_COLS * K_DIM);

  const int cvt_blocks = (N_COLS * K_DIM / 4) / 256;   // 16384
  prep_kernel<<<M_ROWS + cvt_blocks, 256, 0, stream>>>(
      (const float4*)x, (int*)A8, srow, (const int4*)q, (int*)B8);

  dim3 grid(N_COLS / 256, M_ROWS / 256);  // 16 x 32 = 512 blocks
  gemm_i8_kernel<<<grid, 512, 0, stream>>>(A8, B8, scale, srow, bias, out);
}